// Round 16
// baseline (701.778 us; speedup 1.0000x reference)
//
#include <hip/hip_runtime.h>
#include <math.h>

// ---------------------------------------------------------------------------
// Qwen2 decoder layer, bf16-MFMA version (gfx950).
//   H=16 q-heads, HK=4 kv-heads, D=128, HID=2048, INTER=8192, L=4096, NU=3072
//   block-causal mask derived from p & ~2047  (SAMPLE=2048)
// r16: attention rebalanced -- 64 q-rows x 2 waves per block, grid 768 =
//   exactly 3 blocks/CU (was 384 blocks = 1.5/CU: half the CUs ran 2 blocks
//   while half idled). Staging re-indexed for 128 threads; compute per wave
//   unchanged. GEMMs = r12/r15 proven config (single-buffer BK=64, m-major
//   XCD chunk, launch_bounds(256,2)).
// ---------------------------------------------------------------------------

#define NU     3072
#define LPACK  4096
#define HIDN   2048
#define QKV_LD 3072
#define EPSF   1e-6f

typedef unsigned short u16;
typedef unsigned int   u32;
typedef unsigned long long u64;
typedef __attribute__((ext_vector_type(8)))  __bf16 bf16x8;
typedef __attribute__((ext_vector_type(4)))  float  f32x4;
typedef __attribute__((ext_vector_type(16))) float  f32x16;

union FRAG { uint4 q; u16 u[8]; bf16x8 b; };

__device__ __forceinline__ u16 f2bf(float f) {
    u32 u = __float_as_uint(f);
    u32 r = (u + 0x7fffu + ((u >> 16) & 1u)) >> 16;
    return (u16)r;
}
__device__ __forceinline__ float bf2f(u16 h) {
    return __uint_as_float(((u32)h) << 16);
}
__device__ __forceinline__ void gload_lds16(const u16* g, u16* lds) {
    __builtin_amdgcn_global_load_lds(
        (const __attribute__((address_space(1))) u32*)g,
        (__attribute__((address_space(3))) u32*)lds, 16, 0, 0);
}

// ---------------------------- tiny index kernels ---------------------------

__global__ __launch_bounds__(256) void inv_init_kernel(int* __restrict__ inv) {
    inv[blockIdx.x * 256 + threadIdx.x] = -1;            // grid 16
}
__global__ __launch_bounds__(256) void inv_set_kernel(const int* __restrict__ und,
                                                      int* __restrict__ inv) {
    int i = blockIdx.x * 256 + threadIdx.x;              // grid 12
    inv[und[i]] = i;
}

// ------------------ fp32 -> bf16 convert, all weights in one launch --------

struct CvtArgs {
    const float* src[7];
    u16*         dst[7];
    int          n8[7];     // element count / 8
};

__global__ __launch_bounds__(256) void cvt_all_kernel(CvtArgs a) {
    int seg = blockIdx.y;
    const float* in = a.src[seg];
    u16* out = a.dst[seg];
    int n8 = a.n8[seg];
    int idx = blockIdx.x * 256 + threadIdx.x;
    int stride = gridDim.x * 256;
    for (int i = idx; i < n8; i += stride) {
        float4 va = *(const float4*)(in + (size_t)i * 8);
        float4 vb = *(const float4*)(in + (size_t)i * 8 + 4);
        FRAG f;
        f.u[0] = f2bf(va.x); f.u[1] = f2bf(va.y); f.u[2] = f2bf(va.z); f.u[3] = f2bf(va.w);
        f.u[4] = f2bf(vb.x); f.u[5] = f2bf(vb.y); f.u[6] = f2bf(vb.z); f.u[7] = f2bf(vb.w);
        *(uint4*)(out + (size_t)i * 8) = f.q;
    }
}

// ---------------------- row RMSNorm (fp32 in, bf16 out) --------------------

__global__ __launch_bounds__(256) void rmsnorm_bf16_kernel(const float* __restrict__ in,
                                                           const float* __restrict__ w,
                                                           u16* __restrict__ out) {
    int row = blockIdx.x;
    const float4* p = (const float4*)(in + (size_t)row * HIDN);
    float4 a = p[threadIdx.x * 2];
    float4 b = p[threadIdx.x * 2 + 1];
    float ss = a.x*a.x + a.y*a.y + a.z*a.z + a.w*a.w
             + b.x*b.x + b.y*b.y + b.z*b.z + b.w*b.w;
    #pragma unroll
    for (int off = 32; off > 0; off >>= 1) ss += __shfl_xor(ss, off, 64);
    __shared__ float red[4];
    if ((threadIdx.x & 63) == 0) red[threadIdx.x >> 6] = ss;
    __syncthreads();
    float tot = red[0] + red[1] + red[2] + red[3];
    float sc  = rsqrtf(tot * (1.0f / HIDN) + EPSF);
    const float4* wp = (const float4*)w;
    float4 w0 = wp[threadIdx.x * 2], w1 = wp[threadIdx.x * 2 + 1];
    FRAG f;
    f.u[0] = f2bf(a.x*sc*w0.x); f.u[1] = f2bf(a.y*sc*w0.y);
    f.u[2] = f2bf(a.z*sc*w0.z); f.u[3] = f2bf(a.w*sc*w0.w);
    f.u[4] = f2bf(b.x*sc*w1.x); f.u[5] = f2bf(b.y*sc*w1.y);
    f.u[6] = f2bf(b.z*sc*w1.z); f.u[7] = f2bf(b.w*sc*w1.w);
    *(uint4*)(out + (size_t)row * HIDN + threadIdx.x * 8) = f.q;
}

// ---------- per-head RMSNorm of q (bf16 in place), grid-stride -------------

__global__ __launch_bounds__(256) void qnorm_kernel(u16* __restrict__ qkv,
                                                    const float* __restrict__ w) {
    const int lane = threadIdx.x & 63, wv = threadIdx.x >> 6;
    float2 wt = *(const float2*)(w + lane * 2);
    for (int v = blockIdx.x * 4 + wv; v < NU * 16; v += gridDim.x * 4) {
        int i = v >> 4, h = v & 15;
        u16* p = qkv + (size_t)i * QKV_LD + h * 128 + lane * 2;
        u32 pr = *(u32*)p;
        float x0 = bf2f((u16)(pr & 0xffff)), x1 = bf2f((u16)(pr >> 16));
        float ss = x0*x0 + x1*x1;
        #pragma unroll
        for (int off = 32; off > 0; off >>= 1) ss += __shfl_xor(ss, off, 64);
        float sc = rsqrtf(ss * (1.0f / 128.f) + EPSF);
        u32 res = (u32)f2bf(x0*sc*wt.x) | ((u32)f2bf(x1*sc*wt.y) << 16);
        *(u32*)p = res;
    }
}

// ---- scatter K (with RMSNorm) and V into packed [L], bf16, grid-stride ----

__global__ __launch_bounds__(256) void scatter_kv_kernel(const u16* __restrict__ qkvb,
                                                         const int* __restrict__ inv,
                                                         const float* __restrict__ knw,
                                                         u16* __restrict__ Kb,
                                                         u16* __restrict__ Vb) {
    const int lane = threadIdx.x & 63, wv = threadIdx.x >> 6;
    float2 wt = *(const float2*)(knw + lane * 2);
    for (int v = blockIdx.x * 4 + wv; v < LPACK * 4; v += gridDim.x * 4) {
        int l = v >> 2, hkk = v & 3;
        int i = inv[l];
        size_t off = (size_t)l * 512 + hkk * 128 + lane * 2;
        if (i < 0) {
            *(u32*)(Kb + off) = 0u;
            *(u32*)(Vb + off) = 0u;
            continue;
        }
        const u16* kp = qkvb + (size_t)i * QKV_LD + 2048 + hkk * 128 + lane * 2;
        u32 kv = *(const u32*)kp;
        float k0 = bf2f((u16)(kv & 0xffff)), k1 = bf2f((u16)(kv >> 16));
        float ss = k0*k0 + k1*k1;
        #pragma unroll
        for (int off2 = 32; off2 > 0; off2 >>= 1) ss += __shfl_xor(ss, off2, 64);
        float sc = rsqrtf(ss * (1.0f / 128.f) + EPSF);
        u32 res = (u32)f2bf(k0*sc*wt.x) | ((u32)f2bf(k1*sc*wt.y) << 16);
        *(u32*)(Kb + off) = res;
        const u16* vp = qkvb + (size_t)i * QKV_LD + 2560 + hkk * 128 + lane * 2;
        *(u32*)(Vb + off) = *(const u32*)vp;
    }
}

// ------------------------------ bf16 MFMA GEMM -----------------------------
// r12 version: single-buffer, 2 barriers/K-tile, BK=64, 128x128 tile.
// LDS XOR-swizzle: 16B-block j of row r stored at j ^ (r&7) (both sides).
// m-major XCD-chunked swizzle. MODE 0: segmented B + bias, bf16 out.
// MODE 1: +addend, fp32 out.

template <int MODE>
__global__ __launch_bounds__(256, 2) void gemm_bf16_kernel(
        const u16* __restrict__ A, int lda,
        const u16* __restrict__ B0, const u16* __restrict__ B1, const u16* __restrict__ B2,
        int n1, int n2, int ldb,
        const float* __restrict__ bias0, const float* __restrict__ bias1,
        const float* __restrict__ bias2,
        const float* __restrict__ addend,
        void* __restrict__ Cout, int ldc, int K)
{
    __shared__ u16 As[128 * 64];
    __shared__ u16 Bs[128 * 64];
    const int tid = threadIdx.x;
    const int w = tid >> 6, lane = tid & 63;
    const int gx = gridDim.x;
    int id = blockIdx.y * gx + blockIdx.x;
    const int cpx = (gridDim.x * gridDim.y) >> 3;
    id = (id & 7) * cpx + (id >> 3);
    const int m0 = (id / gx) * 128, n0 = (id % gx) * 128;
    const u16* Bp; const float* bias; int nb;
    if (n0 < n1)      { Bp = B0; bias = bias0; nb = n0; }
    else if (n0 < n2) { Bp = B1; bias = bias1; nb = n0 - n1; }
    else              { Bp = B2; bias = bias2; nb = n0 - n2; }
    const int wr = w >> 1, wc = w & 1;
    const int cl = lane & 15, kg = lane >> 4;

    f32x4 acc[4][4];
    #pragma unroll
    for (int i = 0; i < 4; ++i)
        #pragma unroll
        for (int j = 0; j < 4; ++j)
            #pragma unroll
            for (int r = 0; r < 4; ++r) acc[i][j][r] = 0.f;

    for (int k0 = 0; k0 < K; k0 += 64) {
        #pragma unroll
        for (int j = 0; j < 4; ++j) {
            int slot = j * 256 + tid;
            int row = slot >> 3, jp = slot & 7;
            int j2 = jp ^ (row & 7);
            gload_lds16(A + (size_t)(m0 + row) * lda + k0 + j2 * 8,
                        &As[(j * 256 + w * 64) * 8]);
        }
        #pragma unroll
        for (int j = 0; j < 4; ++j) {
            int slot = j * 256 + tid;
            int row = slot >> 3, jp = slot & 7;
            int j2 = jp ^ (row & 7);
            gload_lds16(Bp + (size_t)(nb + row) * ldb + k0 + j2 * 8,
                        &Bs[(j * 256 + w * 64) * 8]);
        }
        __syncthreads();
        #pragma unroll
        for (int ks = 0; ks < 2; ++ks) {
            FRAG af[4], bfr[4];
            #pragma unroll
            for (int mi = 0; mi < 4; ++mi) {
                int row = wr * 64 + mi * 16 + cl;
                int dblk = ks * 4 + kg;
                af[mi].q = *(const uint4*)&As[row * 64 + ((dblk ^ (row & 7)) * 8)];
            }
            #pragma unroll
            for (int ni = 0; ni < 4; ++ni) {
                int row = wc * 64 + ni * 16 + cl;
                int dblk = ks * 4 + kg;
                bfr[ni].q = *(const uint4*)&Bs[row * 64 + ((dblk ^ (row & 7)) * 8)];
            }
            #pragma unroll
            for (int mi = 0; mi < 4; ++mi)
                #pragma unroll
                for (int ni = 0; ni < 4; ++ni)
                    acc[mi][ni] = __builtin_amdgcn_mfma_f32_16x16x32_bf16(
                        af[mi].b, bfr[ni].b, acc[mi][ni], 0, 0, 0);
        }
        __syncthreads();
    }
    #pragma unroll
    for (int mi = 0; mi < 4; ++mi) {
        #pragma unroll
        for (int ni = 0; ni < 4; ++ni) {
            int gcol = n0 + wc * 64 + ni * 16 + cl;
            float bv = 0.f;
            if (MODE == 0) bv = bias[nb + wc * 64 + ni * 16 + cl];
            #pragma unroll
            for (int r = 0; r < 4; ++r) {
                int grow = m0 + wr * 64 + mi * 16 + kg * 4 + r;
                float v = acc[mi][ni][r] + bv;
                if (MODE == 0) {
                    ((u16*)Cout)[(size_t)grow * ldc + gcol] = f2bf(v);
                } else {
                    v += addend[(size_t)grow * ldc + gcol];
                    ((float*)Cout)[(size_t)grow * ldc + gcol] = v;
                }
            }
        }
    }
}

// --------------------- fused gate/up GEMM with SwiGLU (bf16) ---------------
// r12 version: single-buffer, 2 barriers/K-tile, BK=64 (128^2 local optimum).

__global__ __launch_bounds__(256, 2) void gemm_gateup_bf16_kernel(
        const u16* __restrict__ A,
        const u16* __restrict__ Bg, const u16* __restrict__ Bu,
        u16* __restrict__ act, int ldc)
{
    __shared__ u16 As[128 * 64];
    __shared__ u16 Gs[128 * 64];
    __shared__ u16 Us[128 * 64];
    const int tid = threadIdx.x;
    const int w = tid >> 6, lane = tid & 63;
    const int gx = gridDim.x;
    int id = blockIdx.y * gx + blockIdx.x;
    const int cpx = (gridDim.x * gridDim.y) >> 3;
    id = (id & 7) * cpx + (id >> 3);
    const int m0 = (id / gx) * 128, n0 = (id % gx) * 128;
    const int wr = w >> 1, wc = w & 1;
    const int cl = lane & 15, kg = lane >> 4;

    f32x4 ag[4][4], au[4][4];
    #pragma unroll
    for (int i = 0; i < 4; ++i)
        #pragma unroll
        for (int j = 0; j < 4; ++j)
            #pragma unroll
            for (int r = 0; r < 4; ++r) { ag[i][j][r] = 0.f; au[i][j][r] = 0.f; }

    for (int k0 = 0; k0 < HIDN; k0 += 64) {
        #pragma unroll
        for (int j = 0; j < 4; ++j) {
            int slot = j * 256 + tid;
            int row = slot >> 3, jp = slot & 7;
            int j2 = jp ^ (row & 7);
            gload_lds16(A + (size_t)(m0 + row) * HIDN + k0 + j2 * 8,
                        &As[(j * 256 + w * 64) * 8]);
            gload_lds16(Bg + (size_t)(n0 + row) * HIDN + k0 + j2 * 8,
                        &Gs[(j * 256 + w * 64) * 8]);
            gload_lds16(Bu + (size_t)(n0 + row) * HIDN + k0 + j2 * 8,
                        &Us[(j * 256 + w * 64) * 8]);
        }
        __syncthreads();
        #pragma unroll
        for (int ks = 0; ks < 2; ++ks) {
            FRAG af[4], gf[4], uf[4];
            #pragma unroll
            for (int mi = 0; mi < 4; ++mi) {
                int row = wr * 64 + mi * 16 + cl;
                int dblk = ks * 4 + kg;
                af[mi].q = *(const uint4*)&As[row * 64 + ((dblk ^ (row & 7)) * 8)];
            }
            #pragma unroll
            for (int ni = 0; ni < 4; ++ni) {
                int row = wc * 64 + ni * 16 + cl;
                int dblk = ks * 4 + kg;
                gf[ni].q = *(const uint4*)&Gs[row * 64 + ((dblk ^ (row & 7)) * 8)];
                uf[ni].q = *(const uint4*)&Us[row * 64 + ((dblk ^ (row & 7)) * 8)];
            }
            #pragma unroll
            for (int mi = 0; mi < 4; ++mi)
                #pragma unroll
                for (int ni = 0; ni < 4; ++ni) {
                    ag[mi][ni] = __builtin_amdgcn_mfma_f32_16x16x32_bf16(
                        af[mi].b, gf[ni].b, ag[mi][ni], 0, 0, 0);
                    au[mi][ni] = __builtin_amdgcn_mfma_f32_16x16x32_bf16(
                        af[mi].b, uf[ni].b, au[mi][ni], 0, 0, 0);
                }
        }
        __syncthreads();
    }
    #pragma unroll
    for (int mi = 0; mi < 4; ++mi) {
        #pragma unroll
        for (int ni = 0; ni < 4; ++ni) {
            int gcol = n0 + wc * 64 + ni * 16 + cl;
            #pragma unroll
            for (int r = 0; r < 4; ++r) {
                int grow = m0 + wr * 64 + mi * 16 + kg * 4 + r;
                float g = ag[mi][ni][r], u = au[mi][ni][r];
                float s = g / (1.f + __expf(-g));
                act[(size_t)grow * ldc + gcol] = f2bf(s * u);
            }
        }
    }
}

// ------ MFMA flash attention v8: 64 q x 2 waves, balanced 3 blocks/CU ------
// grid (48,16) = 768 blocks = exactly 3/CU (was 384 = 1.5/CU imbalanced).
// Per key-tile: K staged coalesced via global_load_lds (XOR-swizzled);
// V read coalesced (16-thread 128B lines, each thread covers row-pairs r2
// and r2+8) into regs, transposed into LDS Vt[d][k] stride 36. One barrier
// per tile, depth-1 prefetch. XCD chunking: 96 blocks (2 heads) per XCD.

__global__ __launch_bounds__(128, 2) void attn_mfma_kernel(
        const u16* __restrict__ qkv,   // bf16 [3072][3072], q at h*128
        const u16* __restrict__ Kb,    // bf16 [4096][512]
        const u16* __restrict__ Vb,    // bf16 [4096][512]
        const int* __restrict__ und,   // [3072] sorted
        u16* __restrict__ ctxb)        // bf16 [3072][2048]
{
    int id = blockIdx.y * 48 + blockIdx.x;       // 768 blocks
    id = (id & 7) * 96 + (id >> 3);              // XCD chunking: 96/XCD
    const int h = id / 48, hk = h >> 2;
    const int i0 = (id % 48) * 64;
    const int tid = threadIdx.x;                 // 0..127
    const int w = tid >> 6, lane = tid & 63;
    const int ql = lane & 31, hi = lane >> 5;

    __shared__ __align__(16) unsigned char SM[36864];
    u16*  Kt = (u16*)SM;                  // [2][32*128] bf16, 8 KB each
    u16*  Vt = (u16*)(SM + 16384);        // [2][128*36] bf16, 9216 B each
    float* Ot = (float*)SM;               // overlay (epilogue only): [2][32][36]

    const int iq  = i0 + w * 32 + ql;
    const int pqv = und[iq];
    const int rsv = pqv & ~2047;
    const int kend_w = __shfl(pqv, 31, 64);
    const int kbeg_w = __shfl(pqv, 0, 64) & ~2047;
    const int kbeg_b = und[i0] & ~2047;
    const int kend_b = und[i0 + 63];
    const int nt = ((kend_b - kbeg_b) >> 5) + 1;

    FRAG qf[8];
    const u16* qbase = qkv + (size_t)iq * QKV_LD + h * 128;
    #pragma unroll
    for (int ds = 0; ds < 8; ++ds)
        qf[ds].q = *(const uint4*)(qbase + ds * 16 + hi * 8);

    f32x16 Oa[4];
    #pragma unroll
    for (int dg = 0; dg < 4; ++dg)
        #pragma unroll
        for (int r = 0; r < 16; ++r) Oa[dg][r] = 0.f;
    float m_run = -1e30f, l_run = 0.f;
    const float SCALE = 0.08838834764831845f;   // 1/sqrt(128)

    // V-staging roles: 128 thr = (row-pair r2 in 0..7, d-chunk c in 0..15);
    // each thread also covers row-pair r2+8 -> rows 0..31, d 0..127 coalesced.
    const int r2 = tid >> 4, c = tid & 15;

    // ---- prologue: stage tile 0 ----
    FRAG vr0, vr1, vr2, vr3;
    {
        #pragma unroll
        for (int j = 0; j < 4; ++j) {
            int slot = j * 128 + tid;            // 512 slots of 16B
            int r = slot >> 4, jp = slot & 15;
            int jj = jp ^ (r & 15);
            gload_lds16(Kb + (size_t)(kbeg_b + r) * 512 + hk * 128 + jj * 8,
                        &Kt[(j * 128 + w * 64) * 8]);
        }
        const u16* v0 = Vb + (size_t)(kbeg_b + 2 * r2) * 512 + hk * 128 + c * 8;
        const u16* v1 = v0 + (size_t)16 * 512;   // rows 2*(r2+8)
        vr0.q = *(const uint4*)v0;
        vr1.q = *(const uint4*)(v0 + 512);
        vr2.q = *(const uint4*)v1;
        vr3.q = *(const uint4*)(v1 + 512);
    }

    for (int t = 0; t < nt; ++t) {
        const int cur = t & 1;
        const int k0 = kbeg_b + t * 32;
        // commit V(t) regs -> LDS[cur]  (Vt[d][k], stride 36)
        #pragma unroll
        for (int i = 0; i < 8; ++i) {
            u32 val = (u32)vr0.u[i] | ((u32)vr1.u[i] << 16);
            *(u32*)&Vt[cur * 4608 + (c * 8 + i) * 36 + r2 * 2] = val;
            u32 val2 = (u32)vr2.u[i] | ((u32)vr3.u[i] << 16);
            *(u32*)&Vt[cur * 4608 + (c * 8 + i) * 36 + (r2 + 8) * 2] = val2;
        }
        __syncthreads();   // drains this wave's K(t) gloads; all waves' V writes
        // prefetch tile t+1 into the other buffer
        if (t + 1 < nt) {
            int kn = k0 + 32;
            #pragma unroll
            for (int j = 0; j < 4; ++j) {
                int slot = j * 128 + tid;
                int r = slot >> 4, jp = slot & 15;
                int jj = jp ^ (r & 15);
                gload_lds16(Kb + (size_t)(kn + r) * 512 + hk * 128 + jj * 8,
                            &Kt[(cur ^ 1) * 4096 + (j * 128 + w * 64) * 8]);
            }
            const u16* v0 = Vb + (size_t)(kn + 2 * r2) * 512 + hk * 128 + c * 8;
            const u16* v1 = v0 + (size_t)16 * 512;
            vr0.q = *(const uint4*)v0;
            vr1.q = *(const uint4*)(v0 + 512);
            vr2.q = *(const uint4*)v1;
            vr3.q = *(const uint4*)(v1 + 512);
        }
        if (k0 + 31 >= kbeg_w && k0 <= kend_w) {
            // St[key][q] over d=128 : 8 x mfma 32x32x16
            f32x16 st;
            #pragma unroll
            for (int r = 0; r < 16; ++r) st[r] = 0.f;
            __builtin_amdgcn_s_setprio(1);
            #pragma unroll
            for (int ds = 0; ds < 8; ++ds) {
                FRAG kf;
                kf.q = *(const uint4*)&Kt[cur * 4096 + ql * 128 +
                                          (((ds * 2 + hi) ^ (ql & 15)) * 8)];
                st = __builtin_amdgcn_mfma_f32_32x32x16_bf16(kf.b, qf[ds].b, st, 0, 0, 0);
            }
            __builtin_amdgcn_s_setprio(0);
            // mask + online softmax (lane owns q = ql; keys split by hi)
            int kh4 = k0 + (hi << 2);
            #pragma unroll
            for (int r = 0; r < 16; ++r) {
                int key = kh4 + (r & 3) + ((r >> 2) << 3);
                st[r] = (key >= rsv && key <= pqv) ? st[r] * SCALE : -1e30f;
            }
            float ma = fmaxf(fmaxf(st[0], st[1]), fmaxf(st[2], st[3]));
            float mb = fmaxf(fmaxf(st[4], st[5]), fmaxf(st[6], st[7]));
            float mc = fmaxf(fmaxf(st[8], st[9]), fmaxf(st[10], st[11]));
            float md = fmaxf(fmaxf(st[12], st[13]), fmaxf(st[14], st[15]));
            float mloc = fmaxf(fmaxf(ma, mb), fmaxf(mc, md));
            float mfull = fmaxf(mloc, __shfl_xor(mloc, 32, 64));
            float mnew = fmaxf(m_run, mfull);
            float corr = __expf(m_run - mnew);
            #pragma unroll
            for (int r = 0; r < 16; ++r)
                st[r] = (st[r] > -1e29f) ? __expf(st[r] - mnew) : 0.f;
            float sa = (st[0] + st[1]) + (st[2] + st[3]);
            float sb2 = (st[4] + st[5]) + (st[6] + st[7]);
            float sc2 = (st[8] + st[9]) + (st[10] + st[11]);
            float sd = (st[12] + st[13]) + (st[14] + st[15]);
            float psum = (sa + sb2) + (sc2 + sd);
            psum += __shfl_xor(psum, 32, 64);
            l_run = l_run * corr + psum;
            if (__any(mnew > m_run)) {
                #pragma unroll
                for (int r = 0; r < 16; ++r) {
                    float cr = __shfl(corr, (r & 3) + ((r >> 2) << 3) + (hi << 2), 64);
                    #pragma unroll
                    for (int dg = 0; dg < 4; ++dg) Oa[dg][r] *= cr;
                }
            }
            m_run = mnew;
            // build PV A-frags: cvt_pk + permlane32_swap
            u32 pa[2][4];
            #pragma unroll
            for (int s = 0; s < 2; ++s) {
                #pragma unroll
                for (int t2 = 0; t2 < 2; ++t2) {
                    u32 a, b;
                    asm volatile("v_cvt_pk_bf16_f32 %0, %1, %2"
                                 : "=v"(a) : "v"(st[8*s + 2*t2]), "v"(st[8*s + 2*t2 + 1]));
                    asm volatile("v_cvt_pk_bf16_f32 %0, %1, %2"
                                 : "=v"(b) : "v"(st[8*s + 4 + 2*t2]), "v"(st[8*s + 4 + 2*t2 + 1]));
                    asm volatile("v_permlane32_swap_b32 %0, %1" : "+v"(a), "+v"(b));
                    pa[s][t2] = a; pa[s][t2 + 2] = b;
                }
            }
            __builtin_amdgcn_s_setprio(1);
            #pragma unroll
            for (int s = 0; s < 2; ++s) {
                FRAG pau;
                pau.q = make_uint4(pa[s][0], pa[s][1], pa[s][2], pa[s][3]);
                #pragma unroll
                for (int dg = 0; dg < 4; ++dg) {
                    FRAG vfr;
                    const u16* vp = &Vt[cur * 4608 + (dg * 32 + ql) * 36 +
                                        s * 16 + hi * 8];
                    *(u64*)&vfr.u[0] = *(const u64*)vp;
                    *(u64*)&vfr.u[4] = *(const u64*)(vp + 4);
                    Oa[dg] = __builtin_amdgcn_mfma_f32_32x32x16_bf16(
                        pau.b, vfr.b, Oa[dg], 0, 0, 0);
                }
            }
            __builtin_amdgcn_s_setprio(0);
        }
    }
    __syncthreads();   // all compute done before Ot overlays K/V buffers

    // epilogue: transpose through LDS, scale by 1/l, coalesced bf16 store
    float linv = 1.f / l_run;
    #pragma unroll
    for (int dg = 0; dg < 4; ++dg) {
        #pragma unroll
        for (int r = 0; r < 16; ++r)
            Ot[w * 1152 + ((r & 3) + ((r >> 2) << 3) + (hi << 2)) * 36 + ql] = Oa[dg][r];
        __syncthreads();
        float4 v0 = *(const float4*)&Ot[w * 1152 + ql * 36 + hi * 16 + 0];
        float4 v1 = *(const float4*)&Ot[w * 1152 + ql * 36 + hi * 16 + 4];
        float4 v2 = *(const float4*)&Ot[w * 1152 + ql * 36 + hi * 16 + 8];
        float4 v3 = *(const float4*)&Ot[w * 1152 + ql * 36 + hi * 16 + 12];
        FRAG a, b;
        a.u[0] = f2bf(v0.x * linv); a.u[1] = f2bf(v0.y * linv);
        a.u[2] = f2bf(v0.z * linv); a.u[3] = f2bf(v0.w * linv);
        a.u[4] = f2bf(v1.x * linv); a.u[5] = f2bf(v1.y * linv);
        a.u[6] = f2bf(v1.z * linv); a.u[7] = f2bf(v1.w * linv);
        b.u[0] = f2bf(v2.x * linv); b.u[1] = f2bf(v2.y * linv);
        b.u[2] = f2bf(v2.z * linv); b.u[3] = f2bf(v2.w * linv);
        b.u[4] = f2bf(v3.x * linv); b.u[5] = f2bf(v3.y * linv);
        b.u[6] = f2bf(v3.z * linv); b.u[7] = f2bf(v3.w * linv);
        u16* dst = ctxb + (size_t)(i0 + w * 32 + ql) * HIDN + h * 128 + dg * 32 + hi * 16;
        *(uint4*)dst = a.q;
        *(uint4*)(dst + 8) = b.q;
        __syncthreads();
    }
}

// ---------------------------------------------------------------------------

extern "C" void kernel_launch(void* const* d_in, const int* in_sizes, int n_in,
                              void* d_out, int out_size, void* d_ws, size_t ws_size,
                              hipStream_t stream) {
    const float* x    = (const float*)d_in[0];
    const int*   und  = (const int*)d_in[1];
    const float* Wq  = (const float*)d_in[5];
    const float* bq  = (const float*)d_in[6];
    const float* Wk  = (const float*)d_in[7];
    const float* bk  = (const float*)d_in[8];
    const float* Wv  = (const float*)d_in[9];
    const float* bv  = (const float*)d_in[10];
    const float* Wo  = (const float*)d_in[11];
    const float* qnw = (const float*)d_in[12];
    const float* knw = (const float*)d_in[13];
    const float* ln1 = (const float*)d_in[14];
    const float* ln2 = (const float*)d_in[15];
    const float* Wg  = (const float*)d_in[16];
    const float* Wu  = (const float*)d_in[17];
    const float* Wd  = (const float*)d_in[18];
    float* out = (float*)d_out;

    char* W = (char*)d_ws;
    u16* WqB = (u16*)(W + 0);                    //  8,388,608
    u16* WkB = (u16*)(W + 8388608);              //  2,097,152
    u16* WvB = (u16*)(W + 10485760);             //  2,097,152
    u16* WoB = (u16*)(W + 12582912);             //  8,388,608
    u16* WgB = (u16*)(W + 20971520);             // 33,554,432
    u16* WuB = (u16*)(W + 54525952);             // 33,554,432
    u16* WdB = (u16*)(W + 88080384);             // 33,554,432
    char* R1 = W + 121634816;                    // 31,457,280 shared region
    u16* qkvb = (u16*)R1;                        // bf16 [3072][3072]
    u16* ctxb = (u16*)(R1 + 18874368);           // bf16 [3072][2048]
    u16* acth = (u16*)R1;                        // bf16 [3072][4096] (reuse)
    float* hbuf = (float*)(W + 153092096);       // 25,165,824 fp32
    u16* xnb = (u16*)(W + 178257920);            // 12,582,912 region
    u16* Kbf = xnb;                              // bf16 [4096][512] (reuse window)
    u16* Vbf = (u16*)(W + 178257920 + 4194304);
    u16* ynb = xnb;                              // reuse again
    int* inv = (int*)(W + 190840832);

    const int BIG = 1 << 30;

    inv_init_kernel<<<16, 256, 0, stream>>>(inv);
    inv_set_kernel<<<12, 256, 0, stream>>>(und, inv);

    CvtArgs ca;
    ca.src[0] = Wq; ca.dst[0] = WqB; ca.n8[0] = 524288;
    ca.src[1] = Wk; ca.dst[1] = WkB; ca.n8[1] = 131072;
    ca.src[2] = Wv; ca.dst[2] = WvB; ca.n8[2] = 131072;
    ca.src[3] = Wo; ca.dst[3] = WoB; ca.n8[3] = 524288;
    ca.src[4] = Wg; ca.dst[4] = WgB; ca.n8[4] = 2097152;
    ca.src[5] = Wu; ca.dst[5] = WuB; ca.n8[5] = 2097152;
    ca.src[6] = Wd; ca.dst[6] = WdB; ca.n8[6] = 2097152;
    cvt_all_kernel<<<dim3(1024, 7), 256, 0, stream>>>(ca);

    // x -> rmsnorm(ln1) bf16
    rmsnorm_bf16_kernel<<<NU, 256, 0, stream>>>(x, ln1, xnb);
    // fused QKV projection + bias -> bf16 qkv [3072][3072]
    gemm_bf16_kernel<0><<<dim3(24, 24), 256, 0, stream>>>(
        xnb, 2048, WqB, WkB, WvB, 2048, 2560, 2048,
        bq, bk, bv, nullptr, qkvb, QKV_LD, 2048);
    // q-head RMSNorm in place; scatter + norm K, scatter V (bf16, packed L)
    qnorm_kernel<<<2048, 256, 0, stream>>>(qkvb, qnw);
    scatter_kv_kernel<<<1024, 256, 0, stream>>>(qkvb, inv, knw, Kbf, Vbf);
    // MFMA flash attention (balanced 3 blocks/CU) -> ctx bf16
    attn_mfma_kernel<<<dim3(48, 16), 128, 0, stream>>>(qkvb, Kbf, Vbf, und, ctxb);
    // h = ctx @ Wo^T + x  (fp32)
    gemm_bf16_kernel<1><<<dim3(16, 24), 256, 0, stream>>>(
        ctxb, 2048, WoB, WoB, WoB, BIG, BIG, 2048,
        nullptr, nullptr, nullptr, x, hbuf, 2048, 2048);
    // y = rmsnorm(h, ln2) bf16
    rmsnorm_bf16_kernel<<<NU, 256, 0, stream>>>(hbuf, ln2, ynb);
    // MLP in two INTER halves: act = silu(y Wg^T) * (y Wu^T); out (+=) act Wd^T
    gemm_gateup_bf16_kernel<<<dim3(32, 24), 256, 0, stream>>>(
        ynb, WgB, WuB, acth, 4096);
    gemm_bf16_kernel<1><<<dim3(16, 24), 256, 0, stream>>>(
        acth, 4096, WdB, WdB, WdB, BIG, BIG, 8192,
        nullptr, nullptr, nullptr, hbuf, out, 2048, 4096);
    gemm_gateup_bf16_kernel<<<dim3(32, 24), 256, 0, stream>>>(
        ynb, WgB + (size_t)4096 * 2048, WuB + (size_t)4096 * 2048, acth, 4096);
    gemm_bf16_kernel<1><<<dim3(16, 24), 256, 0, stream>>>(
        acth, 4096, WdB + 4096, WdB, WdB, BIG, BIG, 8192,
        nullptr, nullptr, nullptr, out, out, 2048, 4096);
}

// Round 17
// 692.475 us; speedup vs baseline: 1.0134x; 1.0134x over previous
//
#include <hip/hip_runtime.h>
#include <math.h>

// ---------------------------------------------------------------------------
// Qwen2 decoder layer, bf16-MFMA version (gfx950).
//   H=16 q-heads, HK=4 kv-heads, D=128, HID=2048, INTER=8192, L=4096, NU=3072
//   block-causal mask derived from p & ~2047  (SAMPLE=2048)
// r17 = r15 config (best: 695.9 us) + Vt k-column XOR swizzle (u64-granular,
//   g' = g ^ ((d>>3)&7)) applied on BOTH write and read: the old linear
//   commit was an 8-way bank conflict (r16 counters: 1.17e7). K-staging,
//   GEMMs, and all other kernels unchanged from r15.
//   Ledger: r10 launch_bounds(256,3) spills; r11 n-major chunking thrashes
//   L2; r13/r14 dbuf BK=32 slower even conflict-free; r16 64q-rebalance
//   neutral.
// ---------------------------------------------------------------------------

#define NU     3072
#define LPACK  4096
#define HIDN   2048
#define QKV_LD 3072
#define EPSF   1e-6f

typedef unsigned short u16;
typedef unsigned int   u32;
typedef unsigned long long u64;
typedef __attribute__((ext_vector_type(8)))  __bf16 bf16x8;
typedef __attribute__((ext_vector_type(4)))  float  f32x4;
typedef __attribute__((ext_vector_type(16))) float  f32x16;

union FRAG { uint4 q; u16 u[8]; bf16x8 b; };

__device__ __forceinline__ u16 f2bf(float f) {
    u32 u = __float_as_uint(f);
    u32 r = (u + 0x7fffu + ((u >> 16) & 1u)) >> 16;
    return (u16)r;
}
__device__ __forceinline__ float bf2f(u16 h) {
    return __uint_as_float(((u32)h) << 16);
}
__device__ __forceinline__ void gload_lds16(const u16* g, u16* lds) {
    __builtin_amdgcn_global_load_lds(
        (const __attribute__((address_space(1))) u32*)g,
        (__attribute__((address_space(3))) u32*)lds, 16, 0, 0);
}

// ---------------------------- tiny index kernels ---------------------------

__global__ __launch_bounds__(256) void inv_init_kernel(int* __restrict__ inv) {
    inv[blockIdx.x * 256 + threadIdx.x] = -1;            // grid 16
}
__global__ __launch_bounds__(256) void inv_set_kernel(const int* __restrict__ und,
                                                      int* __restrict__ inv) {
    int i = blockIdx.x * 256 + threadIdx.x;              // grid 12
    inv[und[i]] = i;
}

// ------------------ fp32 -> bf16 convert, all weights in one launch --------

struct CvtArgs {
    const float* src[7];
    u16*         dst[7];
    int          n8[7];     // element count / 8
};

__global__ __launch_bounds__(256) void cvt_all_kernel(CvtArgs a) {
    int seg = blockIdx.y;
    const float* in = a.src[seg];
    u16* out = a.dst[seg];
    int n8 = a.n8[seg];
    int idx = blockIdx.x * 256 + threadIdx.x;
    int stride = gridDim.x * 256;
    for (int i = idx; i < n8; i += stride) {
        float4 va = *(const float4*)(in + (size_t)i * 8);
        float4 vb = *(const float4*)(in + (size_t)i * 8 + 4);
        FRAG f;
        f.u[0] = f2bf(va.x); f.u[1] = f2bf(va.y); f.u[2] = f2bf(va.z); f.u[3] = f2bf(va.w);
        f.u[4] = f2bf(vb.x); f.u[5] = f2bf(vb.y); f.u[6] = f2bf(vb.z); f.u[7] = f2bf(vb.w);
        *(uint4*)(out + (size_t)i * 8) = f.q;
    }
}

// ---------------------- row RMSNorm (fp32 in, bf16 out) --------------------

__global__ __launch_bounds__(256) void rmsnorm_bf16_kernel(const float* __restrict__ in,
                                                           const float* __restrict__ w,
                                                           u16* __restrict__ out) {
    int row = blockIdx.x;
    const float4* p = (const float4*)(in + (size_t)row * HIDN);
    float4 a = p[threadIdx.x * 2];
    float4 b = p[threadIdx.x * 2 + 1];
    float ss = a.x*a.x + a.y*a.y + a.z*a.z + a.w*a.w
             + b.x*b.x + b.y*b.y + b.z*b.z + b.w*b.w;
    #pragma unroll
    for (int off = 32; off > 0; off >>= 1) ss += __shfl_xor(ss, off, 64);
    __shared__ float red[4];
    if ((threadIdx.x & 63) == 0) red[threadIdx.x >> 6] = ss;
    __syncthreads();
    float tot = red[0] + red[1] + red[2] + red[3];
    float sc  = rsqrtf(tot * (1.0f / HIDN) + EPSF);
    const float4* wp = (const float4*)w;
    float4 w0 = wp[threadIdx.x * 2], w1 = wp[threadIdx.x * 2 + 1];
    FRAG f;
    f.u[0] = f2bf(a.x*sc*w0.x); f.u[1] = f2bf(a.y*sc*w0.y);
    f.u[2] = f2bf(a.z*sc*w0.z); f.u[3] = f2bf(a.w*sc*w0.w);
    f.u[4] = f2bf(b.x*sc*w1.x); f.u[5] = f2bf(b.y*sc*w1.y);
    f.u[6] = f2bf(b.z*sc*w1.z); f.u[7] = f2bf(b.w*sc*w1.w);
    *(uint4*)(out + (size_t)row * HIDN + threadIdx.x * 8) = f.q;
}

// ---------- per-head RMSNorm of q (bf16 in place), grid-stride -------------

__global__ __launch_bounds__(256) void qnorm_kernel(u16* __restrict__ qkv,
                                                    const float* __restrict__ w) {
    const int lane = threadIdx.x & 63, wv = threadIdx.x >> 6;
    float2 wt = *(const float2*)(w + lane * 2);
    for (int v = blockIdx.x * 4 + wv; v < NU * 16; v += gridDim.x * 4) {
        int i = v >> 4, h = v & 15;
        u16* p = qkv + (size_t)i * QKV_LD + h * 128 + lane * 2;
        u32 pr = *(u32*)p;
        float x0 = bf2f((u16)(pr & 0xffff)), x1 = bf2f((u16)(pr >> 16));
        float ss = x0*x0 + x1*x1;
        #pragma unroll
        for (int off = 32; off > 0; off >>= 1) ss += __shfl_xor(ss, off, 64);
        float sc = rsqrtf(ss * (1.0f / 128.f) + EPSF);
        u32 res = (u32)f2bf(x0*sc*wt.x) | ((u32)f2bf(x1*sc*wt.y) << 16);
        *(u32*)p = res;
    }
}

// ---- scatter K (with RMSNorm) and V into packed [L], bf16, grid-stride ----

__global__ __launch_bounds__(256) void scatter_kv_kernel(const u16* __restrict__ qkvb,
                                                         const int* __restrict__ inv,
                                                         const float* __restrict__ knw,
                                                         u16* __restrict__ Kb,
                                                         u16* __restrict__ Vb) {
    const int lane = threadIdx.x & 63, wv = threadIdx.x >> 6;
    float2 wt = *(const float2*)(knw + lane * 2);
    for (int v = blockIdx.x * 4 + wv; v < LPACK * 4; v += gridDim.x * 4) {
        int l = v >> 2, hkk = v & 3;
        int i = inv[l];
        size_t off = (size_t)l * 512 + hkk * 128 + lane * 2;
        if (i < 0) {
            *(u32*)(Kb + off) = 0u;
            *(u32*)(Vb + off) = 0u;
            continue;
        }
        const u16* kp = qkvb + (size_t)i * QKV_LD + 2048 + hkk * 128 + lane * 2;
        u32 kv = *(const u32*)kp;
        float k0 = bf2f((u16)(kv & 0xffff)), k1 = bf2f((u16)(kv >> 16));
        float ss = k0*k0 + k1*k1;
        #pragma unroll
        for (int off2 = 32; off2 > 0; off2 >>= 1) ss += __shfl_xor(ss, off2, 64);
        float sc = rsqrtf(ss * (1.0f / 128.f) + EPSF);
        u32 res = (u32)f2bf(k0*sc*wt.x) | ((u32)f2bf(k1*sc*wt.y) << 16);
        *(u32*)(Kb + off) = res;
        const u16* vp = qkvb + (size_t)i * QKV_LD + 2560 + hkk * 128 + lane * 2;
        *(u32*)(Vb + off) = *(const u32*)vp;
    }
}

// ------------------------------ bf16 MFMA GEMM -----------------------------
// r12 version: single-buffer, 2 barriers/K-tile, BK=64, 128x128 tile.
// LDS XOR-swizzle: 16B-block j of row r stored at j ^ (r&7) (both sides).
// m-major XCD-chunked swizzle. MODE 0: segmented B + bias, bf16 out.
// MODE 1: +addend, fp32 out.

template <int MODE>
__global__ __launch_bounds__(256, 2) void gemm_bf16_kernel(
        const u16* __restrict__ A, int lda,
        const u16* __restrict__ B0, const u16* __restrict__ B1, const u16* __restrict__ B2,
        int n1, int n2, int ldb,
        const float* __restrict__ bias0, const float* __restrict__ bias1,
        const float* __restrict__ bias2,
        const float* __restrict__ addend,
        void* __restrict__ Cout, int ldc, int K)
{
    __shared__ u16 As[128 * 64];
    __shared__ u16 Bs[128 * 64];
    const int tid = threadIdx.x;
    const int w = tid >> 6, lane = tid & 63;
    const int gx = gridDim.x;
    int id = blockIdx.y * gx + blockIdx.x;
    const int cpx = (gridDim.x * gridDim.y) >> 3;
    id = (id & 7) * cpx + (id >> 3);
    const int m0 = (id / gx) * 128, n0 = (id % gx) * 128;
    const u16* Bp; const float* bias; int nb;
    if (n0 < n1)      { Bp = B0; bias = bias0; nb = n0; }
    else if (n0 < n2) { Bp = B1; bias = bias1; nb = n0 - n1; }
    else              { Bp = B2; bias = bias2; nb = n0 - n2; }
    const int wr = w >> 1, wc = w & 1;
    const int cl = lane & 15, kg = lane >> 4;

    f32x4 acc[4][4];
    #pragma unroll
    for (int i = 0; i < 4; ++i)
        #pragma unroll
        for (int j = 0; j < 4; ++j)
            #pragma unroll
            for (int r = 0; r < 4; ++r) acc[i][j][r] = 0.f;

    for (int k0 = 0; k0 < K; k0 += 64) {
        #pragma unroll
        for (int j = 0; j < 4; ++j) {
            int slot = j * 256 + tid;
            int row = slot >> 3, jp = slot & 7;
            int j2 = jp ^ (row & 7);
            gload_lds16(A + (size_t)(m0 + row) * lda + k0 + j2 * 8,
                        &As[(j * 256 + w * 64) * 8]);
        }
        #pragma unroll
        for (int j = 0; j < 4; ++j) {
            int slot = j * 256 + tid;
            int row = slot >> 3, jp = slot & 7;
            int j2 = jp ^ (row & 7);
            gload_lds16(Bp + (size_t)(nb + row) * ldb + k0 + j2 * 8,
                        &Bs[(j * 256 + w * 64) * 8]);
        }
        __syncthreads();
        #pragma unroll
        for (int ks = 0; ks < 2; ++ks) {
            FRAG af[4], bfr[4];
            #pragma unroll
            for (int mi = 0; mi < 4; ++mi) {
                int row = wr * 64 + mi * 16 + cl;
                int dblk = ks * 4 + kg;
                af[mi].q = *(const uint4*)&As[row * 64 + ((dblk ^ (row & 7)) * 8)];
            }
            #pragma unroll
            for (int ni = 0; ni < 4; ++ni) {
                int row = wc * 64 + ni * 16 + cl;
                int dblk = ks * 4 + kg;
                bfr[ni].q = *(const uint4*)&Bs[row * 64 + ((dblk ^ (row & 7)) * 8)];
            }
            #pragma unroll
            for (int mi = 0; mi < 4; ++mi)
                #pragma unroll
                for (int ni = 0; ni < 4; ++ni)
                    acc[mi][ni] = __builtin_amdgcn_mfma_f32_16x16x32_bf16(
                        af[mi].b, bfr[ni].b, acc[mi][ni], 0, 0, 0);
        }
        __syncthreads();
    }
    #pragma unroll
    for (int mi = 0; mi < 4; ++mi) {
        #pragma unroll
        for (int ni = 0; ni < 4; ++ni) {
            int gcol = n0 + wc * 64 + ni * 16 + cl;
            float bv = 0.f;
            if (MODE == 0) bv = bias[nb + wc * 64 + ni * 16 + cl];
            #pragma unroll
            for (int r = 0; r < 4; ++r) {
                int grow = m0 + wr * 64 + mi * 16 + kg * 4 + r;
                float v = acc[mi][ni][r] + bv;
                if (MODE == 0) {
                    ((u16*)Cout)[(size_t)grow * ldc + gcol] = f2bf(v);
                } else {
                    v += addend[(size_t)grow * ldc + gcol];
                    ((float*)Cout)[(size_t)grow * ldc + gcol] = v;
                }
            }
        }
    }
}

// --------------------- fused gate/up GEMM with SwiGLU (bf16) ---------------
// r12 version: single-buffer, 2 barriers/K-tile, BK=64 (128^2 local optimum).

__global__ __launch_bounds__(256, 2) void gemm_gateup_bf16_kernel(
        const u16* __restrict__ A,
        const u16* __restrict__ Bg, const u16* __restrict__ Bu,
        u16* __restrict__ act, int ldc)
{
    __shared__ u16 As[128 * 64];
    __shared__ u16 Gs[128 * 64];
    __shared__ u16 Us[128 * 64];
    const int tid = threadIdx.x;
    const int w = tid >> 6, lane = tid & 63;
    const int gx = gridDim.x;
    int id = blockIdx.y * gx + blockIdx.x;
    const int cpx = (gridDim.x * gridDim.y) >> 3;
    id = (id & 7) * cpx + (id >> 3);
    const int m0 = (id / gx) * 128, n0 = (id % gx) * 128;
    const int wr = w >> 1, wc = w & 1;
    const int cl = lane & 15, kg = lane >> 4;

    f32x4 ag[4][4], au[4][4];
    #pragma unroll
    for (int i = 0; i < 4; ++i)
        #pragma unroll
        for (int j = 0; j < 4; ++j)
            #pragma unroll
            for (int r = 0; r < 4; ++r) { ag[i][j][r] = 0.f; au[i][j][r] = 0.f; }

    for (int k0 = 0; k0 < HIDN; k0 += 64) {
        #pragma unroll
        for (int j = 0; j < 4; ++j) {
            int slot = j * 256 + tid;
            int row = slot >> 3, jp = slot & 7;
            int j2 = jp ^ (row & 7);
            gload_lds16(A + (size_t)(m0 + row) * HIDN + k0 + j2 * 8,
                        &As[(j * 256 + w * 64) * 8]);
            gload_lds16(Bg + (size_t)(n0 + row) * HIDN + k0 + j2 * 8,
                        &Gs[(j * 256 + w * 64) * 8]);
            gload_lds16(Bu + (size_t)(n0 + row) * HIDN + k0 + j2 * 8,
                        &Us[(j * 256 + w * 64) * 8]);
        }
        __syncthreads();
        #pragma unroll
        for (int ks = 0; ks < 2; ++ks) {
            FRAG af[4], gf[4], uf[4];
            #pragma unroll
            for (int mi = 0; mi < 4; ++mi) {
                int row = wr * 64 + mi * 16 + cl;
                int dblk = ks * 4 + kg;
                af[mi].q = *(const uint4*)&As[row * 64 + ((dblk ^ (row & 7)) * 8)];
            }
            #pragma unroll
            for (int ni = 0; ni < 4; ++ni) {
                int row = wc * 64 + ni * 16 + cl;
                int dblk = ks * 4 + kg;
                gf[ni].q = *(const uint4*)&Gs[row * 64 + ((dblk ^ (row & 7)) * 8)];
                uf[ni].q = *(const uint4*)&Us[row * 64 + ((dblk ^ (row & 7)) * 8)];
            }
            #pragma unroll
            for (int mi = 0; mi < 4; ++mi)
                #pragma unroll
                for (int ni = 0; ni < 4; ++ni) {
                    ag[mi][ni] = __builtin_amdgcn_mfma_f32_16x16x32_bf16(
                        af[mi].b, gf[ni].b, ag[mi][ni], 0, 0, 0);
                    au[mi][ni] = __builtin_amdgcn_mfma_f32_16x16x32_bf16(
                        af[mi].b, uf[ni].b, au[mi][ni], 0, 0, 0);
                }
        }
        __syncthreads();
    }
    #pragma unroll
    for (int mi = 0; mi < 4; ++mi) {
        #pragma unroll
        for (int ni = 0; ni < 4; ++ni) {
            int gcol = n0 + wc * 64 + ni * 16 + cl;
            #pragma unroll
            for (int r = 0; r < 4; ++r) {
                int grow = m0 + wr * 64 + mi * 16 + kg * 4 + r;
                float g = ag[mi][ni][r], u = au[mi][ni][r];
                float s = g / (1.f + __expf(-g));
                act[(size_t)grow * ldc + gcol] = f2bf(s * u);
            }
        }
    }
}

// -------- MFMA flash attention v9: r15 structure + Vt column swizzle -------
// Block = 128 q-rows x 1 head, 4 waves, grid (24,16). Vt[d][k] stride 36;
// k-pair p of row d stored with u64-group g' = (p>>1) ^ ((d>>3)&7) --
// write banks spread ~2-way (was 8-way linear); read applies same involution
// (u64 granularity preserves within-group k order -> MFMA layout unchanged).

__global__ __launch_bounds__(256, 2) void attn_mfma_kernel(
        const u16* __restrict__ qkv,   // bf16 [3072][3072], q at h*128
        const u16* __restrict__ Kb,    // bf16 [4096][512]
        const u16* __restrict__ Vb,    // bf16 [4096][512]
        const int* __restrict__ und,   // [3072] sorted
        u16* __restrict__ ctxb)        // bf16 [3072][2048]
{
    int id = blockIdx.y * 24 + blockIdx.x;       // 384 blocks
    id = (id & 7) * 48 + (id >> 3);              // XCD chunking
    const int h = id / 24, hk = h >> 2;
    const int i0 = (id % 24) * 128;
    const int tid = threadIdx.x;
    const int w = tid >> 6, lane = tid & 63;
    const int ql = lane & 31, hi = lane >> 5;

    __shared__ __align__(16) unsigned char SM[36864];
    u16*  Kt = (u16*)SM;                  // [2][32*128] bf16, 8 KB each
    u16*  Vt = (u16*)(SM + 16384);        // [2][128*36] bf16, 9216 B each
    float* Ot = (float*)SM;               // overlay (epilogue only): [4][32][36]

    const int iq  = i0 + w * 32 + ql;
    const int pqv = und[iq];
    const int rsv = pqv & ~2047;
    const int kend_w = __shfl(pqv, 31, 64);
    const int kbeg_w = __shfl(pqv, 0, 64) & ~2047;
    const int kbeg_b = und[i0] & ~2047;
    const int kend_b = und[i0 + 127];
    const int nt = ((kend_b - kbeg_b) >> 5) + 1;

    FRAG qf[8];
    const u16* qbase = qkv + (size_t)iq * QKV_LD + h * 128;
    #pragma unroll
    for (int ds = 0; ds < 8; ++ds)
        qf[ds].q = *(const uint4*)(qbase + ds * 16 + hi * 8);

    f32x16 Oa[4];
    #pragma unroll
    for (int dg = 0; dg < 4; ++dg)
        #pragma unroll
        for (int r = 0; r < 16; ++r) Oa[dg][r] = 0.f;
    float m_run = -1e30f, l_run = 0.f;
    const float SCALE = 0.08838834764831845f;   // 1/sqrt(128)

    // V-staging roles: thread = (k-row-pair r2 in 0..15, d-chunk c in 0..15)
    const int r2 = tid >> 4, c = tid & 15;
    // swizzled column (elements) for this thread's k-pair r2 in rows c*8+i:
    // u64 group g = r2>>1, g' = g ^ (c & 7); col = g'*4 + (r2&1)*2.
    const int vcol = (((r2 >> 1) ^ (c & 7)) << 2) + ((r2 & 1) << 1);

    // ---- prologue: stage tile 0 ----
    FRAG vr0, vr1;
    {
        #pragma unroll
        for (int j = 0; j < 2; ++j) {
            int sb = (j * 4 + w) * 64;
            int slot = sb + lane;
            int r = slot >> 4, jp = slot & 15;
            int jj = jp ^ (r & 15);
            gload_lds16(Kb + (size_t)(kbeg_b + r) * 512 + hk * 128 + jj * 8,
                        &Kt[sb * 8]);
        }
        const u16* v0 = Vb + (size_t)(kbeg_b + 2 * r2) * 512 + hk * 128 + c * 8;
        vr0.q = *(const uint4*)v0;
        vr1.q = *(const uint4*)(v0 + 512);
    }

    for (int t = 0; t < nt; ++t) {
        const int cur = t & 1;
        const int k0 = kbeg_b + t * 32;
        // commit V(t) regs -> LDS[cur]  (Vt[d][.], stride 36, swizzled col)
        #pragma unroll
        for (int i = 0; i < 8; ++i) {
            u32 val = (u32)vr0.u[i] | ((u32)vr1.u[i] << 16);
            *(u32*)&Vt[cur * 4608 + (c * 8 + i) * 36 + vcol] = val;
        }
        __syncthreads();   // drains this wave's K(t) gloads; all waves' V writes
        // prefetch tile t+1 into the other buffer
        if (t + 1 < nt) {
            int kn = k0 + 32;
            #pragma unroll
            for (int j = 0; j < 2; ++j) {
                int sb = (j * 4 + w) * 64;
                int slot = sb + lane;
                int r = slot >> 4, jp = slot & 15;
                int jj = jp ^ (r & 15);
                gload_lds16(Kb + (size_t)(kn + r) * 512 + hk * 128 + jj * 8,
                            &Kt[(cur ^ 1) * 4096 + sb * 8]);
            }
            const u16* v0 = Vb + (size_t)(kn + 2 * r2) * 512 + hk * 128 + c * 8;
            vr0.q = *(const uint4*)v0;
            vr1.q = *(const uint4*)(v0 + 512);
        }
        if (k0 + 31 >= kbeg_w && k0 <= kend_w) {
            // St[key][q] over d=128 : 8 x mfma 32x32x16
            f32x16 st;
            #pragma unroll
            for (int r = 0; r < 16; ++r) st[r] = 0.f;
            __builtin_amdgcn_s_setprio(1);
            #pragma unroll
            for (int ds = 0; ds < 8; ++ds) {
                FRAG kf;
                kf.q = *(const uint4*)&Kt[cur * 4096 + ql * 128 +
                                          (((ds * 2 + hi) ^ (ql & 15)) * 8)];
                st = __builtin_amdgcn_mfma_f32_32x32x16_bf16(kf.b, qf[ds].b, st, 0, 0, 0);
            }
            __builtin_amdgcn_s_setprio(0);
            // mask + online softmax (lane owns q = ql; keys split by hi)
            int kh4 = k0 + (hi << 2);
            #pragma unroll
            for (int r = 0; r < 16; ++r) {
                int key = kh4 + (r & 3) + ((r >> 2) << 3);
                st[r] = (key >= rsv && key <= pqv) ? st[r] * SCALE : -1e30f;
            }
            float ma = fmaxf(fmaxf(st[0], st[1]), fmaxf(st[2], st[3]));
            float mb = fmaxf(fmaxf(st[4], st[5]), fmaxf(st[6], st[7]));
            float mc = fmaxf(fmaxf(st[8], st[9]), fmaxf(st[10], st[11]));
            float md = fmaxf(fmaxf(st[12], st[13]), fmaxf(st[14], st[15]));
            float mloc = fmaxf(fmaxf(ma, mb), fmaxf(mc, md));
            float mfull = fmaxf(mloc, __shfl_xor(mloc, 32, 64));
            float mnew = fmaxf(m_run, mfull);
            float corr = __expf(m_run - mnew);
            #pragma unroll
            for (int r = 0; r < 16; ++r)
                st[r] = (st[r] > -1e29f) ? __expf(st[r] - mnew) : 0.f;
            float sa = (st[0] + st[1]) + (st[2] + st[3]);
            float sb2 = (st[4] + st[5]) + (st[6] + st[7]);
            float sc2 = (st[8] + st[9]) + (st[10] + st[11]);
            float sd = (st[12] + st[13]) + (st[14] + st[15]);
            float psum = (sa + sb2) + (sc2 + sd);
            psum += __shfl_xor(psum, 32, 64);
            l_run = l_run * corr + psum;
            if (__any(mnew > m_run)) {
                #pragma unroll
                for (int r = 0; r < 16; ++r) {
                    float cr = __shfl(corr, (r & 3) + ((r >> 2) << 3) + (hi << 2), 64);
                    #pragma unroll
                    for (int dg = 0; dg < 4; ++dg) Oa[dg][r] *= cr;
                }
            }
            m_run = mnew;
            // build PV A-frags: cvt_pk + permlane32_swap
            u32 pa[2][4];
            #pragma unroll
            for (int s = 0; s < 2; ++s) {
                #pragma unroll
                for (int t2 = 0; t2 < 2; ++t2) {
                    u32 a, b;
                    asm volatile("v_cvt_pk_bf16_f32 %0, %1, %2"
                                 : "=v"(a) : "v"(st[8*s + 2*t2]), "v"(st[8*s + 2*t2 + 1]));
                    asm volatile("v_cvt_pk_bf16_f32 %0, %1, %2"
                                 : "=v"(b) : "v"(st[8*s + 4 + 2*t2]), "v"(st[8*s + 4 + 2*t2 + 1]));
                    asm volatile("v_permlane32_swap_b32 %0, %1" : "+v"(a), "+v"(b));
                    pa[s][t2] = a; pa[s][t2 + 2] = b;
                }
            }
            __builtin_amdgcn_s_setprio(1);
            #pragma unroll
            for (int s = 0; s < 2; ++s) {
                FRAG pau;
                pau.q = make_uint4(pa[s][0], pa[s][1], pa[s][2], pa[s][3]);
                #pragma unroll
                for (int dg = 0; dg < 4; ++dg) {
                    FRAG vfr;
                    int d = dg * 32 + ql;
                    int xs = (d >> 3) & 7;
                    int g0 = s * 4 + hi * 2;
                    const u16* vrow = &Vt[cur * 4608 + d * 36];
                    *(u64*)&vfr.u[0] = *(const u64*)(vrow + ((g0 ^ xs) << 2));
                    *(u64*)&vfr.u[4] = *(const u64*)(vrow + (((g0 + 1) ^ xs) << 2));
                    Oa[dg] = __builtin_amdgcn_mfma_f32_32x32x16_bf16(
                        pau.b, vfr.b, Oa[dg], 0, 0, 0);
                }
            }
            __builtin_amdgcn_s_setprio(0);
        }
    }
    __syncthreads();   // all compute done before Ot overlays K/V buffers

    // epilogue: transpose through LDS, scale by 1/l, coalesced bf16 store
    float linv = 1.f / l_run;
    #pragma unroll
    for (int dg = 0; dg < 4; ++dg) {
        #pragma unroll
        for (int r = 0; r < 16; ++r)
            Ot[w * 1152 + ((r & 3) + ((r >> 2) << 3) + (hi << 2)) * 36 + ql] = Oa[dg][r];
        __syncthreads();
        float4 v0 = *(const float4*)&Ot[w * 1152 + ql * 36 + hi * 16 + 0];
        float4 v1 = *(const float4*)&Ot[w * 1152 + ql * 36 + hi * 16 + 4];
        float4 v2 = *(const float4*)&Ot[w * 1152 + ql * 36 + hi * 16 + 8];
        float4 v3 = *(const float4*)&Ot[w * 1152 + ql * 36 + hi * 16 + 12];
        FRAG a, b;
        a.u[0] = f2bf(v0.x * linv); a.u[1] = f2bf(v0.y * linv);
        a.u[2] = f2bf(v0.z * linv); a.u[3] = f2bf(v0.w * linv);
        a.u[4] = f2bf(v1.x * linv); a.u[5] = f2bf(v1.y * linv);
        a.u[6] = f2bf(v1.z * linv); a.u[7] = f2bf(v1.w * linv);
        b.u[0] = f2bf(v2.x * linv); b.u[1] = f2bf(v2.y * linv);
        b.u[2] = f2bf(v2.z * linv); b.u[3] = f2bf(v2.w * linv);
        b.u[4] = f2bf(v3.x * linv); b.u[5] = f2bf(v3.y * linv);
        b.u[6] = f2bf(v3.z * linv); b.u[7] = f2bf(v3.w * linv);
        u16* dst = ctxb + (size_t)(i0 + w * 32 + ql) * HIDN + h * 128 + dg * 32 + hi * 16;
        *(uint4*)dst = a.q;
        *(uint4*)(dst + 8) = b.q;
        __syncthreads();
    }
}

// ---------------------------------------------------------------------------

extern "C" void kernel_launch(void* const* d_in, const int* in_sizes, int n_in,
                              void* d_out, int out_size, void* d_ws, size_t ws_size,
                              hipStream_t stream) {
    const float* x    = (const float*)d_in[0];
    const int*   und  = (const int*)d_in[1];
    const float* Wq  = (const float*)d_in[5];
    const float* bq  = (const float*)d_in[6];
    const float* Wk  = (const float*)d_in[7];
    const float* bk  = (const float*)d_in[8];
    const float* Wv  = (const float*)d_in[9];
    const float* bv  = (const float*)d_in[10];
    const float* Wo  = (const float*)d_in[11];
    const float* qnw = (const float*)d_in[12];
    const float* knw = (const float*)d_in[13];
    const float* ln1 = (const float*)d_in[14];
    const float* ln2 = (const float*)d_in[15];
    const float* Wg  = (const float*)d_in[16];
    const float* Wu  = (const float*)d_in[17];
    const float* Wd  = (const float*)d_in[18];
    float* out = (float*)d_out;

    char* W = (char*)d_ws;
    u16* WqB = (u16*)(W + 0);                    //  8,388,608
    u16* WkB = (u16*)(W + 8388608);              //  2,097,152
    u16* WvB = (u16*)(W + 10485760);             //  2,097,152
    u16* WoB = (u16*)(W + 12582912);             //  8,388,608
    u16* WgB = (u16*)(W + 20971520);             // 33,554,432
    u16* WuB = (u16*)(W + 54525952);             // 33,554,432
    u16* WdB = (u16*)(W + 88080384);             // 33,554,432
    char* R1 = W + 121634816;                    // 31,457,280 shared region
    u16* qkvb = (u16*)R1;                        // bf16 [3072][3072]
    u16* ctxb = (u16*)(R1 + 18874368);           // bf16 [3072][2048]
    u16* acth = (u16*)R1;                        // bf16 [3072][4096] (reuse)
    float* hbuf = (float*)(W + 153092096);       // 25,165,824 fp32
    u16* xnb = (u16*)(W + 178257920);            // 12,582,912 region
    u16* Kbf = xnb;                              // bf16 [4096][512] (reuse window)
    u16* Vbf = (u16*)(W + 178257920 + 4194304);
    u16* ynb = xnb;                              // reuse again
    int* inv = (int*)(W + 190840832);

    const int BIG = 1 << 30;

    inv_init_kernel<<<16, 256, 0, stream>>>(inv);
    inv_set_kernel<<<12, 256, 0, stream>>>(und, inv);

    CvtArgs ca;
    ca.src[0] = Wq; ca.dst[0] = WqB; ca.n8[0] = 524288;
    ca.src[1] = Wk; ca.dst[1] = WkB; ca.n8[1] = 131072;
    ca.src[2] = Wv; ca.dst[2] = WvB; ca.n8[2] = 131072;
    ca.src[3] = Wo; ca.dst[3] = WoB; ca.n8[3] = 524288;
    ca.src[4] = Wg; ca.dst[4] = WgB; ca.n8[4] = 2097152;
    ca.src[5] = Wu; ca.dst[5] = WuB; ca.n8[5] = 2097152;
    ca.src[6] = Wd; ca.dst[6] = WdB; ca.n8[6] = 2097152;
    cvt_all_kernel<<<dim3(1024, 7), 256, 0, stream>>>(ca);

    // x -> rmsnorm(ln1) bf16
    rmsnorm_bf16_kernel<<<NU, 256, 0, stream>>>(x, ln1, xnb);
    // fused QKV projection + bias -> bf16 qkv [3072][3072]
    gemm_bf16_kernel<0><<<dim3(24, 24), 256, 0, stream>>>(
        xnb, 2048, WqB, WkB, WvB, 2048, 2560, 2048,
        bq, bk, bv, nullptr, qkvb, QKV_LD, 2048);
    // q-head RMSNorm in place; scatter + norm K, scatter V (bf16, packed L)
    qnorm_kernel<<<2048, 256, 0, stream>>>(qkvb, qnw);
    scatter_kv_kernel<<<1024, 256, 0, stream>>>(qkvb, inv, knw, Kbf, Vbf);
    // MFMA flash attention -> ctx bf16
    attn_mfma_kernel<<<dim3(24, 16), 256, 0, stream>>>(qkvb, Kbf, Vbf, und, ctxb);
    // h = ctx @ Wo^T + x  (fp32)
    gemm_bf16_kernel<1><<<dim3(16, 24), 256, 0, stream>>>(
        ctxb, 2048, WoB, WoB, WoB, BIG, BIG, 2048,
        nullptr, nullptr, nullptr, x, hbuf, 2048, 2048);
    // y = rmsnorm(h, ln2) bf16
    rmsnorm_bf16_kernel<<<NU, 256, 0, stream>>>(hbuf, ln2, ynb);
    // MLP in two INTER halves: act = silu(y Wg^T) * (y Wu^T); out (+=) act Wd^T
    gemm_gateup_bf16_kernel<<<dim3(32, 24), 256, 0, stream>>>(
        ynb, WgB, WuB, acth, 4096);
    gemm_bf16_kernel<1><<<dim3(16, 24), 256, 0, stream>>>(
        acth, 4096, WdB, WdB, WdB, BIG, BIG, 8192,
        nullptr, nullptr, nullptr, hbuf, out, 2048, 4096);
    gemm_gateup_bf16_kernel<<<dim3(32, 24), 256, 0, stream>>>(
        ynb, WgB + (size_t)4096 * 2048, WuB + (size_t)4096 * 2048, acth, 4096);
    gemm_bf16_kernel<1><<<dim3(16, 24), 256, 0, stream>>>(
        acth, 4096, WdB + 4096, WdB, WdB, BIG, BIG, 8192,
        nullptr, nullptr, nullptr, out, out, 2048, 4096);
}